// Round 4
// baseline (310.562 us; speedup 1.0000x reference)
//
#include <hip/hip_runtime.h>

#define NTOT 131072   // B*T = 16*8192
#define KCB  512
#define DIM  64

__device__ __forceinline__ float wave_sum(float v) {
#pragma unroll
  for (int off = 32; off; off >>= 1) v += __shfl_xor(v, off, 64);
  return v;
}

// ---------------------------------------------------------------------------
// K1: distances + argmin + one-hot + idx + per-block-partial counts/dw.
// 256 blocks x 512 threads (8 waves). NO in-loop barriers: x staging is
// wave-private LDS (compiler fences pin ds_write/ds_read order; HW executes
// per-wave LDS ops in issue order); dw/cnt go to per-block partial buffers.
// LDS: embt 128K + xls 32K = 160 KiB exactly.
// ---------------------------------------------------------------------------
__global__ __launch_bounds__(512, 2) void k_dist(
    const float* __restrict__ x_g,      // [D][N]
    const float* __restrict__ emb_g,    // [K][D]
    float* __restrict__ dist_out,       // [N][K]
    float* __restrict__ enc_out,        // [N][K]
    int* __restrict__ idx_out,          // [N]
    unsigned* __restrict__ cnt_p,       // [npart][K]
    float* __restrict__ dw_p,           // [npart][K][D]
    int npart)
{
  __shared__ __align__(16) float embt[DIM][KCB];   // -2*emb[k][d] at [d][k], 128 KiB
  __shared__ __align__(16) float xls[8][16][DIM];  // per-wave x rows, 32 KiB

  const int t = threadIdx.x;
  const int lane = t & 63;
  const int w = t >> 6;
  const int part = blockIdx.x & (npart - 1);

  // ---- stage embedding (once): thread t owns code row t
  {
    const float* er = emb_g + t * DIM;
#pragma unroll
    for (int d0 = 0; d0 < DIM; d0 += 4) {
      const float4 e = *reinterpret_cast<const float4*>(er + d0);
      embt[d0 + 0][t] = -2.f * e.x;
      embt[d0 + 1][t] = -2.f * e.y;
      embt[d0 + 2][t] = -2.f * e.z;
      embt[d0 + 3][t] = -2.f * e.w;
    }
  }
  __syncthreads();   // the only block-wide barrier

  // ---- per-lane |emb|^2 for its 8 k's, from embt: sq = 0.25 * sum((-2e)^2)
  float ebr[8] = {0.f, 0.f, 0.f, 0.f, 0.f, 0.f, 0.f, 0.f};
  for (int d = 0; d < DIM; ++d) {
    const float4 a = *reinterpret_cast<const float4*>(&embt[d][4 * lane]);
    const float4 b = *reinterpret_cast<const float4*>(&embt[d][256 + 4 * lane]);
    ebr[0] = fmaf(a.x, a.x, ebr[0]); ebr[1] = fmaf(a.y, a.y, ebr[1]);
    ebr[2] = fmaf(a.z, a.z, ebr[2]); ebr[3] = fmaf(a.w, a.w, ebr[3]);
    ebr[4] = fmaf(b.x, b.x, ebr[4]); ebr[5] = fmaf(b.y, b.y, ebr[5]);
    ebr[6] = fmaf(b.z, b.z, ebr[6]); ebr[7] = fmaf(b.w, b.w, ebr[7]);
  }
#pragma unroll
  for (int j = 0; j < 8; ++j) ebr[j] *= 0.25f;

  const int nb = blockIdx.x * 512;
  const int r_own = lane & 15;          // this lane's row within wave tile
  const int dgrp  = lane >> 4;          // 0..3

  for (int tt = 0; tt < 4; ++tt) {
    const int n0w = nb + tt * 128 + w * 16;   // wave's 16 rows

    // fence: prior iteration's xls reads complete before we overwrite
    asm volatile("" ::: "memory");

    // ---- wave-private x load: full 64B-segment coalescing
    float xv[16];
#pragma unroll
    for (int j = 0; j < 16; ++j)
      xv[j] = x_g[(size_t)(4 * j + dgrp) * NTOT + n0w + r_own];
#pragma unroll
    for (int j = 0; j < 16; ++j)
      xls[w][r_own][4 * j + dgrp] = xv[j];

    // fence: staging writes ordered before GEMM reads (wave-synchronous LDS)
    asm volatile("" ::: "memory");

    // ---- per-row |x|^2 via butterfly over the 4 d-groups
    float ps = 0.f;
#pragma unroll
    for (int j = 0; j < 16; ++j) ps = fmaf(xv[j], xv[j], ps);
    ps += __shfl_xor(ps, 16, 64);
    ps += __shfl_xor(ps, 32, 64);       // ps = |x[row r_own]|^2 in all 4 dgrp lanes

    // ---- accumulators: init with |e_k|^2
    float acc[16][8];
#pragma unroll
    for (int r = 0; r < 16; ++r)
#pragma unroll
      for (int j = 0; j < 8; ++j) acc[r][j] = ebr[j];

    // ---- GEMM: acc[r][j] += x[r][d] * (-2 e[k_j][d])
    for (int q = 0; q < 16; ++q) {      // d-blocks of 4 (not unrolled: I$)
      float4 e0[4], e1[4];
#pragma unroll
      for (int dq = 0; dq < 4; ++dq) {
        e0[dq] = *reinterpret_cast<const float4*>(&embt[4 * q + dq][4 * lane]);
        e1[dq] = *reinterpret_cast<const float4*>(&embt[4 * q + dq][256 + 4 * lane]);
      }
#pragma unroll
      for (int r = 0; r < 16; ++r) {
        const float4 xb = *reinterpret_cast<const float4*>(&xls[w][r][4 * q]);
        acc[r][0] = fmaf(xb.x, e0[0].x, acc[r][0]);
        acc[r][1] = fmaf(xb.x, e0[0].y, acc[r][1]);
        acc[r][2] = fmaf(xb.x, e0[0].z, acc[r][2]);
        acc[r][3] = fmaf(xb.x, e0[0].w, acc[r][3]);
        acc[r][4] = fmaf(xb.x, e1[0].x, acc[r][4]);
        acc[r][5] = fmaf(xb.x, e1[0].y, acc[r][5]);
        acc[r][6] = fmaf(xb.x, e1[0].z, acc[r][6]);
        acc[r][7] = fmaf(xb.x, e1[0].w, acc[r][7]);

        acc[r][0] = fmaf(xb.y, e0[1].x, acc[r][0]);
        acc[r][1] = fmaf(xb.y, e0[1].y, acc[r][1]);
        acc[r][2] = fmaf(xb.y, e0[1].z, acc[r][2]);
        acc[r][3] = fmaf(xb.y, e0[1].w, acc[r][3]);
        acc[r][4] = fmaf(xb.y, e1[1].x, acc[r][4]);
        acc[r][5] = fmaf(xb.y, e1[1].y, acc[r][5]);
        acc[r][6] = fmaf(xb.y, e1[1].z, acc[r][6]);
        acc[r][7] = fmaf(xb.y, e1[1].w, acc[r][7]);

        acc[r][0] = fmaf(xb.z, e0[2].x, acc[r][0]);
        acc[r][1] = fmaf(xb.z, e0[2].y, acc[r][1]);
        acc[r][2] = fmaf(xb.z, e0[2].z, acc[r][2]);
        acc[r][3] = fmaf(xb.z, e0[2].w, acc[r][3]);
        acc[r][4] = fmaf(xb.z, e1[2].x, acc[r][4]);
        acc[r][5] = fmaf(xb.z, e1[2].y, acc[r][5]);
        acc[r][6] = fmaf(xb.z, e1[2].z, acc[r][6]);
        acc[r][7] = fmaf(xb.z, e1[2].w, acc[r][7]);

        acc[r][0] = fmaf(xb.w, e0[3].x, acc[r][0]);
        acc[r][1] = fmaf(xb.w, e0[3].y, acc[r][1]);
        acc[r][2] = fmaf(xb.w, e0[3].z, acc[r][2]);
        acc[r][3] = fmaf(xb.w, e0[3].w, acc[r][3]);
        acc[r][4] = fmaf(xb.w, e1[3].x, acc[r][4]);
        acc[r][5] = fmaf(xb.w, e1[3].y, acc[r][5]);
        acc[r][6] = fmaf(xb.w, e1[3].z, acc[r][6]);
        acc[r][7] = fmaf(xb.w, e1[3].w, acc[r][7]);
      }
    }

    // ---- epilogue per row: +|x|^2, argmin, stores, partial dw/cnt
#pragma unroll
    for (int r = 0; r < 16; ++r) {
      const int nr = n0w + r;
      const float xs = __uint_as_float(
          __builtin_amdgcn_readlane(__float_as_uint(ps), r));
      float dv[8];
#pragma unroll
      for (int j = 0; j < 8; ++j) dv[j] = acc[r][j] + xs;

      unsigned long long best = ~0ull;
#pragma unroll
      for (int j = 0; j < 8; ++j) {
        const unsigned kk = (j < 4) ? (unsigned)(4 * lane + j)
                                    : (unsigned)(256 + 4 * lane + (j - 4));
        const unsigned long long pk =
            ((unsigned long long)__float_as_uint(dv[j]) << 32) | kk;
        best = pk < best ? pk : best;
      }
#pragma unroll
      for (int off = 32; off; off >>= 1) {
        const unsigned long long o = __shfl_xor(best, off, 64);
        best = o < best ? o : best;
      }
      const int kmin = (int)(best & 0xFFFFFFFFull);

      float* dp = dist_out + (size_t)nr * KCB + 4 * lane;
      float2 p;
      p.x = dv[0]; p.y = dv[1]; *reinterpret_cast<float2*>(dp) = p;
      p.x = dv[2]; p.y = dv[3]; *reinterpret_cast<float2*>(dp + 2) = p;
      p.x = dv[4]; p.y = dv[5]; *reinterpret_cast<float2*>(dp + 256) = p;
      p.x = dv[6]; p.y = dv[7]; *reinterpret_cast<float2*>(dp + 258) = p;

      float* ep = enc_out + (size_t)nr * KCB + 4 * lane;
      const int k0 = 4 * lane;
      float2 z;
      z.x = (kmin == k0)           ? 1.f : 0.f;
      z.y = (kmin == k0 + 1)       ? 1.f : 0.f;
      *reinterpret_cast<float2*>(ep) = z;
      z.x = (kmin == k0 + 2)       ? 1.f : 0.f;
      z.y = (kmin == k0 + 3)       ? 1.f : 0.f;
      *reinterpret_cast<float2*>(ep + 2) = z;
      z.x = (kmin == 256 + k0)     ? 1.f : 0.f;
      z.y = (kmin == 256 + k0 + 1) ? 1.f : 0.f;
      *reinterpret_cast<float2*>(ep + 256) = z;
      z.x = (kmin == 256 + k0 + 2) ? 1.f : 0.f;
      z.y = (kmin == 256 + k0 + 3) ? 1.f : 0.f;
      *reinterpret_cast<float2*>(ep + 258) = z;

      if (lane == 0) {
        idx_out[nr] = kmin;
        atomicAdd(cnt_p + (size_t)part * KCB + kmin, 1u);
      }
      const float xrow = xls[w][r][lane];   // x[nr][d=lane]
      unsafeAtomicAdd(dw_p + (size_t)part * (KCB * DIM) + (kmin << 6) + lane, xrow);
    }
  }
}

// ---------------------------------------------------------------------------
// K2: reduce per-block partials -> dwsum[512][64], cnt[512]
// ---------------------------------------------------------------------------
__global__ __launch_bounds__(256, 8) void k_red(
    const float* __restrict__ dw_p, const unsigned* __restrict__ cnt_p,
    float* __restrict__ dwsum, unsigned* __restrict__ cnt, int npart)
{
  const int t = blockIdx.x * 256 + threadIdx.x;   // 128 blocks -> 32768 threads
  float s = 0.f;
#pragma unroll 4
  for (int p = 0; p < npart; ++p) s += dw_p[(size_t)p * (KCB * DIM) + t];
  dwsum[t] = s;
  if (t < KCB) {
    unsigned c = 0u;
#pragma unroll 4
    for (int p = 0; p < npart; ++p) c += cnt_p[(size_t)p * KCB + t];
    cnt[t] = c;
  }
}

// ---------------------------------------------------------------------------
// K3: cluster EMA + laplace + new_emb + perplexity (1 block, 512 threads)
// ---------------------------------------------------------------------------
__global__ __launch_bounds__(512, 1) void k_final(
    const float* __restrict__ ema_w, const float* __restrict__ ema_cs,
    const unsigned* __restrict__ cnt, const float* __restrict__ dw,
    float* __restrict__ nemb, float* __restrict__ out)
{
  __shared__ float red[8];
  __shared__ float bc;
  const int t = threadIdx.x;
  const int lane = t & 63, w = t >> 6;

  const float c = (float)cnt[t];
  const float craw = ema_cs[t] * 0.99f + 0.01f * c;

  float s = wave_sum(craw);
  if (lane == 0) red[w] = s;
  __syncthreads();
  if (t == 0) {
    float a = 0.f;
#pragma unroll
    for (int i = 0; i < 8; ++i) a += red[i];
    bc = a;
  }
  __syncthreads();
  const float n = bc;
  const float clus = (craw + 1e-5f) / (n + 512.f * 1e-5f) * n;

  const float4* wr = reinterpret_cast<const float4*>(ema_w + t * 64);
  const float4* dr = reinterpret_cast<const float4*>(dw + t * 64);
  float4* nr = reinterpret_cast<float4*>(nemb + t * 64);
#pragma unroll
  for (int q = 0; q < 16; ++q) {
    const float4 wv = wr[q], dv = dr[q];
    float4 o;
    o.x = (wv.x * 0.99f + 0.01f * dv.x) / clus;
    o.y = (wv.y * 0.99f + 0.01f * dv.y) / clus;
    o.z = (wv.z * 0.99f + 0.01f * dv.z) / clus;
    o.w = (wv.w * 0.99f + 0.01f * dv.w) / clus;
    nr[q] = o;
  }

  const float p = c * (1.f / 131072.f);
  const float term = p * logf(p + 1e-10f);
  float s2 = wave_sum(term);
  if (lane == 0) red[w] = s2;
  __syncthreads();
  if (t == 0) {
    float a = 0.f;
#pragma unroll
    for (int i = 0; i < 8; ++i) a += red[i];
    out[8388609] = expf(-a);   // perplexity slot
  }
}

// ---------------------------------------------------------------------------
// K4: quantized gather + transposed write + commitment loss
// ---------------------------------------------------------------------------
__global__ __launch_bounds__(256, 4) void k_quant(
    const float* __restrict__ x_g, const int* __restrict__ idx_g,
    const float* __restrict__ nemb, float* __restrict__ out)
{
  float lsum = 0.f;
  const int stride = gridDim.x * 256;
  for (int i = blockIdx.x * 256 + threadIdx.x; i < (DIM * NTOT / 4); i += stride) {
    const int d = i >> 15;                 // / (NTOT/4)
    const int n4 = i & ((NTOT / 4) - 1);
    const float4 xv = *reinterpret_cast<const float4*>(x_g + ((size_t)d << 17) + 4 * n4);
    const int4 id = *reinterpret_cast<const int4*>(idx_g + 4 * n4);
    const float q0 = nemb[(id.x << 6) + d];
    const float q1 = nemb[(id.y << 6) + d];
    const float q2 = nemb[(id.z << 6) + d];
    const float q3 = nemb[(id.w << 6) + d];
    const float e0 = q0 - xv.x, e1 = q1 - xv.y, e2 = q2 - xv.z, e3 = q3 - xv.w;
    float* op = out + 1 + ((size_t)d << 17) + 4 * n4;   // quantized_st region
    op[0] = xv.x + e0;  // mimic x + (q - x) exactly
    op[1] = xv.y + e1;
    op[2] = xv.z + e2;
    op[3] = xv.w + e3;
    lsum += e0 * e0 + e1 * e1 + e2 * e2 + e3 * e3;
  }
  lsum = wave_sum(lsum);
  __shared__ float wsum[4];
  const int lane = threadIdx.x & 63, w = threadIdx.x >> 6;
  if (lane == 0) wsum[w] = lsum;
  __syncthreads();
  if (threadIdx.x == 0)
    unsafeAtomicAdd(out, (wsum[0] + wsum[1] + wsum[2] + wsum[3]) * (0.25f / 8388608.f));
}

// ---------------------------------------------------------------------------
extern "C" void kernel_launch(void* const* d_in, const int* in_sizes, int n_in,
                              void* d_out, int out_size, void* d_ws, size_t ws_size,
                              hipStream_t stream) {
  const float* x      = (const float*)d_in[0];   // [64][16][8192]
  const float* emb    = (const float*)d_in[1];   // [512][64]
  const float* ema_w  = (const float*)d_in[2];   // [512][64]
  const float* ema_cs = (const float*)d_in[3];   // [512]
  float* out = (float*)d_out;

  // d_out layout: loss@0 | q@1 (8388608) | perp@8388609 | enc@8388610 | dist@75497474
  float* enc_out  = out + 8388610;
  float* dist_out = out + 75497474;

  // ws layout:
  //   dwsum  @0        131072 B
  //   cnt    @131072     2048 B
  //   nemb   @133120   131072 B
  //   idx    @264192   524288 B
  //   cnt_p  @788480   npart*2048 B
  //   dw_p   @788480+npart*2048   npart*131072 B
  char* ws = (char*)d_ws;
  float*    dwsum = (float*)ws;
  unsigned* cnt   = (unsigned*)(ws + 131072);
  float*    nemb  = (float*)(ws + 133120);
  int*      idx   = (int*)(ws + 264192);

  int npart = 256;
  while (npart > 1 &&
         (size_t)788480 + (size_t)npart * 133120 > ws_size) npart >>= 1;
  unsigned* cnt_p = (unsigned*)(ws + 788480);
  float*    dw_p  = (float*)(ws + 788480 + (size_t)npart * 2048);

  // zero partials + loss accumulator
  hipMemsetAsync(ws + 788480, 0, (size_t)npart * 133120, stream);
  hipMemsetAsync(d_out, 0, sizeof(float), stream);

  k_dist<<<256, 512, 0, stream>>>(x, emb, dist_out, enc_out, idx, cnt_p, dw_p, npart);
  k_red<<<128, 256, 0, stream>>>(dw_p, cnt_p, dwsum, cnt, npart);
  k_final<<<1, 512, 0, stream>>>(ema_w, ema_cs, cnt, dwsum, nemb, out);
  k_quant<<<2048, 256, 0, stream>>>(x, idx, nemb, out);
}

// Round 6
// 238.953 us; speedup vs baseline: 1.2997x; 1.2997x over previous
//
#include <hip/hip_runtime.h>

#define NTOT 131072   // B*T = 16*8192
#define KCB  512
#define DIM  64

__device__ __forceinline__ float wave_sum(float v) {
#pragma unroll
  for (int off = 32; off; off >>= 1) v += __shfl_xor(v, off, 64);
  return v;
}

// ---------------------------------------------------------------------------
// K1: distances + argmin + one-hot + idx + counts + dw scatter.
// 256 blocks x 512 threads (8 waves). Barrier-free main loop:
//   - x staging is wave-private LDS (compiler fences pin ds order; HW runs a
//     wave's LDS ops in issue order) -> stores stream, no vmcnt(0) drains.
//   - acc[8][8] per lane (round-2-proven register budget, no spills).
//   - dist/enc stores are float4: each instruction covers a contiguous 1KB
//     wave window (vs float2 at 16B stride = half-line write amplification).
// LDS: embt 128K + xls 16.3K + lcnt 2K = 146.3 KiB.
// ---------------------------------------------------------------------------
__global__ __launch_bounds__(512, 2) void k_dist(
    const float* __restrict__ x_g,      // [D][N]
    const float* __restrict__ emb_g,    // [K][D]
    float* __restrict__ dist_out,       // [N][K]
    float* __restrict__ enc_out,        // [N][K]
    int* __restrict__ idx_out,          // [N]
    unsigned* __restrict__ cnt_g,       // [K]
    float* __restrict__ dw_g)           // [K][D]
{
  __shared__ __align__(16) float embt[DIM][KCB];   // -2*emb[k][d] at [d][k]
  __shared__ __align__(16) float xls[8][8][65];    // per-wave 8 rows, padded
  __shared__ unsigned lcnt[KCB];

  const int t = threadIdx.x;
  const int lane = t & 63;
  const int w = t >> 6;

  lcnt[t] = 0u;

  // ---- stage embedding (once): thread t owns code row t
  {
    const float* er = emb_g + t * DIM;
#pragma unroll
    for (int d0 = 0; d0 < DIM; d0 += 4) {
      const float4 e = *reinterpret_cast<const float4*>(er + d0);
      embt[d0 + 0][t] = -2.f * e.x;
      embt[d0 + 1][t] = -2.f * e.y;
      embt[d0 + 2][t] = -2.f * e.z;
      embt[d0 + 3][t] = -2.f * e.w;
    }
  }
  __syncthreads();   // the only block-wide barrier (until the final one)

  // ---- per-lane |emb|^2 for its 8 k's: sq = 0.25 * sum((-2e)^2)
  float ebr[8] = {0.f, 0.f, 0.f, 0.f, 0.f, 0.f, 0.f, 0.f};
  for (int d = 0; d < DIM; ++d) {
    const float4 a = *reinterpret_cast<const float4*>(&embt[d][4 * lane]);
    const float4 b = *reinterpret_cast<const float4*>(&embt[d][256 + 4 * lane]);
    ebr[0] = fmaf(a.x, a.x, ebr[0]); ebr[1] = fmaf(a.y, a.y, ebr[1]);
    ebr[2] = fmaf(a.z, a.z, ebr[2]); ebr[3] = fmaf(a.w, a.w, ebr[3]);
    ebr[4] = fmaf(b.x, b.x, ebr[4]); ebr[5] = fmaf(b.y, b.y, ebr[5]);
    ebr[6] = fmaf(b.z, b.z, ebr[6]); ebr[7] = fmaf(b.w, b.w, ebr[7]);
  }
#pragma unroll
  for (int j = 0; j < 8; ++j) ebr[j] *= 0.25f;

  const int nb = blockIdx.x * 512;
  const int r_own = lane & 7;           // this lane's row within wave tile
  const int dgc   = lane >> 3;          // d-chunk 0..7

  for (int tt = 0; tt < 8; ++tt) {
    const int n0w = nb + tt * 64 + w * 8;   // wave's 8 rows

    // fence: prior iteration's xls reads retire before overwrite
    asm volatile("" ::: "memory");

    // ---- wave-private x load: lane loads row r_own, d-chunk dgc (8 vals)
    float xv[8];
#pragma unroll
    for (int j = 0; j < 8; ++j)
      xv[j] = x_g[(size_t)(dgc * 8 + j) * NTOT + n0w + r_own];
#pragma unroll
    for (int j = 0; j < 8; ++j)
      xls[w][r_own][dgc * 8 + j] = xv[j];

    // fence: staging writes ordered before reads (wave-synchronous LDS)
    asm volatile("" ::: "memory");

    // ---- |x|^2 for row r_own: partial over chunk, butterfly over chunks
    float ps = 0.f;
#pragma unroll
    for (int j = 0; j < 8; ++j) ps = fmaf(xv[j], xv[j], ps);
    ps += __shfl_xor(ps, 8, 64);
    ps += __shfl_xor(ps, 16, 64);
    ps += __shfl_xor(ps, 32, 64);       // lane r holds |x[row r]|^2 (r = lane&7)

    // ---- transpose via LDS: lane l holds x[row r][d=l]
    float xr[8];
#pragma unroll
    for (int r = 0; r < 8; ++r) xr[r] = xls[w][r][lane];

    // ---- accumulators init with |e_k|^2
    float acc[8][8];
#pragma unroll
    for (int r = 0; r < 8; ++r)
#pragma unroll
      for (int j = 0; j < 8; ++j) acc[r][j] = ebr[j];

    // ---- GEMM: acc[r][j] += x[r][d] * (-2 e[k_j][d])
#pragma unroll 4
    for (int d = 0; d < DIM; ++d) {
      const float4 e0 = *reinterpret_cast<const float4*>(&embt[d][4 * lane]);
      const float4 e1 = *reinterpret_cast<const float4*>(&embt[d][256 + 4 * lane]);
#pragma unroll
      for (int r = 0; r < 8; ++r) {
        const float s = __uint_as_float(
            __builtin_amdgcn_readlane(__float_as_uint(xr[r]), d));
        acc[r][0] = fmaf(s, e0.x, acc[r][0]);
        acc[r][1] = fmaf(s, e0.y, acc[r][1]);
        acc[r][2] = fmaf(s, e0.z, acc[r][2]);
        acc[r][3] = fmaf(s, e0.w, acc[r][3]);
        acc[r][4] = fmaf(s, e1.x, acc[r][4]);
        acc[r][5] = fmaf(s, e1.y, acc[r][5]);
        acc[r][6] = fmaf(s, e1.z, acc[r][6]);
        acc[r][7] = fmaf(s, e1.w, acc[r][7]);
      }
    }

    // ---- epilogue per row: +|x|^2, argmin, float4 stores, idx/cnt/dw
#pragma unroll
    for (int r = 0; r < 8; ++r) {
      const int nr = n0w + r;
      const float xs = __uint_as_float(
          __builtin_amdgcn_readlane(__float_as_uint(ps), r));
      float dv[8];
#pragma unroll
      for (int j = 0; j < 8; ++j) dv[j] = acc[r][j] + xs;

      // argmin, first-min tie-break: pack (dist_bits, k); dists > 0
      unsigned long long best = ~0ull;
#pragma unroll
      for (int j = 0; j < 8; ++j) {
        const unsigned kk = (j < 4) ? (unsigned)(4 * lane + j)
                                    : (unsigned)(256 + 4 * lane + (j - 4));
        const unsigned long long pk =
            ((unsigned long long)__float_as_uint(dv[j]) << 32) | kk;
        best = pk < best ? pk : best;
      }
#pragma unroll
      for (int off = 32; off; off >>= 1) {
        const unsigned long long o = __shfl_xor(best, off, 64);
        best = o < best ? o : best;
      }
      const int kmin = (int)(best & 0xFFFFFFFFull);

      // contiguous 1KB wave windows (regions are 8B-aligned; unaligned
      // dwordx4 is legal on gfx9+ global ops)
      float* dp = dist_out + (size_t)nr * KCB + 4 * lane;
      float4 q;
      q.x = dv[0]; q.y = dv[1]; q.z = dv[2]; q.w = dv[3];
      *reinterpret_cast<float4*>(dp) = q;
      q.x = dv[4]; q.y = dv[5]; q.z = dv[6]; q.w = dv[7];
      *reinterpret_cast<float4*>(dp + 256) = q;

      float* ep = enc_out + (size_t)nr * KCB + 4 * lane;
      const int k0 = 4 * lane;
      float4 z;
      z.x = (kmin == k0)     ? 1.f : 0.f;
      z.y = (kmin == k0 + 1) ? 1.f : 0.f;
      z.z = (kmin == k0 + 2) ? 1.f : 0.f;
      z.w = (kmin == k0 + 3) ? 1.f : 0.f;
      *reinterpret_cast<float4*>(ep) = z;
      z.x = (kmin == 256 + k0)     ? 1.f : 0.f;
      z.y = (kmin == 256 + k0 + 1) ? 1.f : 0.f;
      z.z = (kmin == 256 + k0 + 2) ? 1.f : 0.f;
      z.w = (kmin == 256 + k0 + 3) ? 1.f : 0.f;
      *reinterpret_cast<float4*>(ep + 256) = z;

      if (lane == 0) {
        idx_out[nr] = kmin;
        atomicAdd(&lcnt[kmin], 1u);
      }
      // dw[kmin][d] += x[nr][d], d = lane
      unsafeAtomicAdd(dw_g + ((size_t)kmin << 6) + lane, xr[r]);
    }
  }

  __syncthreads();
  if (lcnt[t]) atomicAdd(&cnt_g[t], lcnt[t]);
}

// ---------------------------------------------------------------------------
// K3: cluster EMA + laplace + new_emb + perplexity (1 block, 512 threads)
// ---------------------------------------------------------------------------
__global__ __launch_bounds__(512, 1) void k_final(
    const float* __restrict__ ema_w, const float* __restrict__ ema_cs,
    const unsigned* __restrict__ cnt, const float* __restrict__ dw,
    float* __restrict__ nemb, float* __restrict__ out)
{
  __shared__ float red[8];
  __shared__ float bc;
  const int t = threadIdx.x;
  const int lane = t & 63, w = t >> 6;

  const float c = (float)cnt[t];
  const float craw = ema_cs[t] * 0.99f + 0.01f * c;

  float s = wave_sum(craw);
  if (lane == 0) red[w] = s;
  __syncthreads();
  if (t == 0) {
    float a = 0.f;
#pragma unroll
    for (int i = 0; i < 8; ++i) a += red[i];
    bc = a;
  }
  __syncthreads();
  const float n = bc;
  const float clus = (craw + 1e-5f) / (n + 512.f * 1e-5f) * n;

  const float4* wr = reinterpret_cast<const float4*>(ema_w + t * 64);
  const float4* dr = reinterpret_cast<const float4*>(dw + t * 64);
  float4* nr = reinterpret_cast<float4*>(nemb + t * 64);
#pragma unroll
  for (int q = 0; q < 16; ++q) {
    const float4 wv = wr[q], dv = dr[q];
    float4 o;
    o.x = (wv.x * 0.99f + 0.01f * dv.x) / clus;
    o.y = (wv.y * 0.99f + 0.01f * dv.y) / clus;
    o.z = (wv.z * 0.99f + 0.01f * dv.z) / clus;
    o.w = (wv.w * 0.99f + 0.01f * dv.w) / clus;
    nr[q] = o;
  }

  const float p = c * (1.f / 131072.f);
  const float term = p * logf(p + 1e-10f);
  float s2 = wave_sum(term);
  if (lane == 0) red[w] = s2;
  __syncthreads();
  if (t == 0) {
    float a = 0.f;
#pragma unroll
    for (int i = 0; i < 8; ++i) a += red[i];
    out[8388609] = expf(-a);   // perplexity slot
  }
}

// ---------------------------------------------------------------------------
// K4: quantized gather + transposed write + commitment loss
// ---------------------------------------------------------------------------
__global__ __launch_bounds__(256, 4) void k_quant(
    const float* __restrict__ x_g, const int* __restrict__ idx_g,
    const float* __restrict__ nemb, float* __restrict__ out)
{
  float lsum = 0.f;
  const int stride = gridDim.x * 256;
  for (int i = blockIdx.x * 256 + threadIdx.x; i < (DIM * NTOT / 4); i += stride) {
    const int d = i >> 15;                 // / (NTOT/4)
    const int n4 = i & ((NTOT / 4) - 1);
    const float4 xv = *reinterpret_cast<const float4*>(x_g + ((size_t)d << 17) + 4 * n4);
    const int4 id = *reinterpret_cast<const int4*>(idx_g + 4 * n4);
    const float q0 = nemb[(id.x << 6) + d];
    const float q1 = nemb[(id.y << 6) + d];
    const float q2 = nemb[(id.z << 6) + d];
    const float q3 = nemb[(id.w << 6) + d];
    const float e0 = q0 - xv.x, e1 = q1 - xv.y, e2 = q2 - xv.z, e3 = q3 - xv.w;
    float* op = out + 1 + ((size_t)d << 17) + 4 * n4;   // quantized_st region
    op[0] = xv.x + e0;  // mimic x + (q - x) exactly
    op[1] = xv.y + e1;
    op[2] = xv.z + e2;
    op[3] = xv.w + e3;
    lsum += e0 * e0 + e1 * e1 + e2 * e2 + e3 * e3;
  }
  lsum = wave_sum(lsum);
  __shared__ float wsum[4];
  const int lane = threadIdx.x & 63, w = threadIdx.x >> 6;
  if (lane == 0) wsum[w] = lsum;
  __syncthreads();
  if (threadIdx.x == 0)
    unsafeAtomicAdd(out, (wsum[0] + wsum[1] + wsum[2] + wsum[3]) * (0.25f / 8388608.f));
}

// ---------------------------------------------------------------------------
extern "C" void kernel_launch(void* const* d_in, const int* in_sizes, int n_in,
                              void* d_out, int out_size, void* d_ws, size_t ws_size,
                              hipStream_t stream) {
  const float* x      = (const float*)d_in[0];   // [64][16][8192]
  const float* emb    = (const float*)d_in[1];   // [512][64]
  const float* ema_w  = (const float*)d_in[2];   // [512][64]
  const float* ema_cs = (const float*)d_in[3];   // [512]
  float* out = (float*)d_out;

  // d_out layout: loss@0 | q@1 (8388608) | perp@8388609 | enc@8388610 | dist@75497474
  float* enc_out  = out + 8388610;
  float* dist_out = out + 75497474;

  // ws layout: dw [512*64]f @0 | counts [512]u @131072 | new_emb @133120 | idx @264192
  char* ws = (char*)d_ws;
  float*    dw   = (float*)ws;
  unsigned* cnt  = (unsigned*)(ws + 131072);
  float*    nemb = (float*)(ws + 133120);
  int*      idx  = (int*)(ws + 264192);

  hipMemsetAsync(d_ws, 0, 133120, stream);          // zero dw + counts
  hipMemsetAsync(d_out, 0, sizeof(float), stream);  // zero loss accumulator

  k_dist<<<256, 512, 0, stream>>>(x, emb, dist_out, enc_out, idx, cnt, dw);
  k_final<<<1, 512, 0, stream>>>(ema_w, ema_cs, cnt, dw, nemb, out);
  k_quant<<<2048, 256, 0, stream>>>(x, idx, nemb, out);
}